// Round 1
// baseline (344.702 us; speedup 1.0000x reference)
//
#include <hip/hip_runtime.h>
#include <hip/hip_bf16.h>

typedef __attribute__((ext_vector_type(8))) short short8;
typedef __attribute__((ext_vector_type(4))) float f32x4;

#define MFMA_16x16x32(A, B, C) __builtin_amdgcn_mfma_f32_16x16x32_bf16((A), (B), (C), 0, 0, 0)

__device__ __forceinline__ short f2bf(float x) {
  unsigned u = __float_as_uint(x);
  return (short)((u + 0x7FFFu + ((u >> 16) & 1u)) >> 16);  // RNE; inputs finite
}

// ---------------- weight transpose + bf16 convert: W[1024][128] -> WT[128][1024] ----------------
__global__ __launch_bounds__(256) void wt_kernel(
    const float* __restrict__ Wq, const float* __restrict__ Wk, const float* __restrict__ Wv,
    short* __restrict__ WqT, short* __restrict__ WkT, short* __restrict__ WvT)
{
  const float* W  = (blockIdx.y == 0) ? Wq  : (blockIdx.y == 1) ? Wk  : Wv;
  short*       WT = (blockIdx.y == 0) ? WqT : (blockIdx.y == 1) ? WkT : WvT;
  int idx = blockIdx.x * 256 + threadIdx.x;   // 0..131071
  int n = idx >> 10, k = idx & 1023;
  WT[idx] = f2bf(W[k * 128 + n]);
}

// ---------------- fused QKV projection ----------------
// y=0: Qs[m][n] = (query@Wq + bq) * scale_q   (scale folds 1/sqrt(128)*log2(e))
// y=1: Ks[m][n] = key@Wk + bk
// y=2: VTs[n][m] = value@Wv + bv              (stored TRANSPOSED for the attention PV step)
__global__ __launch_bounds__(256) void proj_kernel(
    const float* __restrict__ Aq, const float* __restrict__ Ak, const float* __restrict__ Av,
    const short* __restrict__ WqT, const short* __restrict__ WkT, const short* __restrict__ WvT,
    const float* __restrict__ bq, const float* __restrict__ bk, const float* __restrict__ bv,
    short* __restrict__ Qs, short* __restrict__ Ks, short* __restrict__ VTs,
    float scale_q)
{
  __shared__ short Alds[64 * 40];    // [64][32] bf16, row stride 40 (2-way banks: free)
  __shared__ short Wlds[128 * 40];   // [128][32] bf16 (WT k-slice)
  const int y = blockIdx.y;
  const float* A    = (y == 0) ? Aq  : (y == 1) ? Ak  : Av;
  const short* WT   = (y == 0) ? WqT : (y == 1) ? WkT : WvT;
  const float* bias = (y == 0) ? bq  : (y == 1) ? bk  : bv;
  const int tid = threadIdx.x;
  const int lane = tid & 63, w = tid >> 6;
  const int g = (lane >> 4) & 3, ql = lane & 15;
  const long m0 = (long)blockIdx.x * 64;

  const f32x4 fzero = {0.f, 0.f, 0.f, 0.f};
  f32x4 acc[8];
  #pragma unroll
  for (int i = 0; i < 8; ++i) acc[i] = fzero;

  const int arow = tid >> 2, ac0 = (tid & 3) * 8;
  const int wn1 = (w >> 1) * 64, wm1 = (w & 1) * 32;  // mode y<2 tiling
  const int wn2 = w * 32;                              // mode y==2 tiling

  for (int kk = 0; kk < 1024; kk += 32) {
    __syncthreads();
    {  // stage A tile [64][32] fp32 -> bf16
      const float* src = A + (m0 + arow) * 1024 + kk + ac0;
      float4 a0 = *(const float4*)(src);
      float4 a1 = *(const float4*)(src + 4);
      short8 pb;
      pb[0] = f2bf(a0.x); pb[1] = f2bf(a0.y); pb[2] = f2bf(a0.z); pb[3] = f2bf(a0.w);
      pb[4] = f2bf(a1.x); pb[5] = f2bf(a1.y); pb[6] = f2bf(a1.z); pb[7] = f2bf(a1.w);
      *(short8*)&Alds[arow * 40 + ac0] = pb;
    }
    #pragma unroll
    for (int cc = 0; cc < 2; ++cc) {  // stage WT k-slice [128][32]
      int c = tid + cc * 256;
      int n = c >> 2, i0 = (c & 3) * 8;
      *(short8*)&Wlds[n * 40 + i0] = *(const short8*)(WT + n * 1024 + kk + i0);
    }
    __syncthreads();
    if (y < 2) {
      short8 af[2], bf[4];
      #pragma unroll
      for (int mt = 0; mt < 2; ++mt)
        af[mt] = *(const short8*)&Alds[(wm1 + 16 * mt + ql) * 40 + g * 8];
      #pragma unroll
      for (int nt = 0; nt < 4; ++nt)
        bf[nt] = *(const short8*)&Wlds[(wn1 + 16 * nt + ql) * 40 + g * 8];
      #pragma unroll
      for (int mt = 0; mt < 2; ++mt)
        #pragma unroll
        for (int nt = 0; nt < 4; ++nt)
          acc[mt * 4 + nt] = MFMA_16x16x32(af[mt], bf[nt], acc[mt * 4 + nt]);
    } else {
      // V^T = (Wv^T) · (value^T): A-operand = WT rows (dv), B-operand = value rows as columns
      short8 af[2], bf[4];
      #pragma unroll
      for (int nt = 0; nt < 2; ++nt)
        af[nt] = *(const short8*)&Wlds[(wn2 + 16 * nt + ql) * 40 + g * 8];
      #pragma unroll
      for (int mt = 0; mt < 4; ++mt)
        bf[mt] = *(const short8*)&Alds[(16 * mt + ql) * 40 + g * 8];
      #pragma unroll
      for (int nt = 0; nt < 2; ++nt)
        #pragma unroll
        for (int mt = 0; mt < 4; ++mt)
          acc[nt * 4 + mt] = MFMA_16x16x32(af[nt], bf[mt], acc[nt * 4 + mt]);
    }
  }

  if (y < 2) {
    short* Out = (y == 0) ? Qs : Ks;
    const float sc = (y == 0) ? scale_q : 1.0f;
    #pragma unroll
    for (int nt = 0; nt < 4; ++nt) {
      int n = wn1 + 16 * nt + ql;
      float bs = bias[n];
      #pragma unroll
      for (int mt = 0; mt < 2; ++mt)
        #pragma unroll
        for (int r = 0; r < 4; ++r) {
          long m = m0 + wm1 + 16 * mt + 4 * g + r;
          Out[m * 128 + n] = f2bf((acc[mt * 4 + nt][r] + bs) * sc);
        }
    }
  } else {
    #pragma unroll
    for (int nt = 0; nt < 2; ++nt)
      #pragma unroll
      for (int r = 0; r < 4; ++r) {
        int n = wn2 + 16 * nt + 4 * g + r;
        float bs = bias[n];
        #pragma unroll
        for (int mt = 0; mt < 4; ++mt) {
          long m = m0 + 16 * mt + ql;
          VTs[(long)n * 32768 + m] = f2bf(acc[nt * 4 + mt][r] + bs);
        }
      }
  }
}

// ---------------- flash attention ----------------
// Q pre-scaled by 1/sqrt(128)*log2(e); softmax in exp2 domain.
// Per wave: 16 q-rows. S^T = K·Q^T (swapped) so lane owns q-column => shuffle-free row stats.
// O^T = V^T·P^T with V^T staged directly from the transposed V in ws.
__global__ __launch_bounds__(256) void attn_kernel(
    const short* __restrict__ Q,    // [8*4096][128] bf16 (scaled)
    const short* __restrict__ K,    // [8*4096][128] bf16
    const short* __restrict__ VT,   // [128][8*4096] bf16
    float* __restrict__ O)          // [8*4096][128] f32
{
  __shared__ short Klds[32 * 136];   // [32][128] bf16, stride 136 (2-way on reads)
  __shared__ short Vlds[128 * 40];   // [128][32] bf16, stride 40
  const int tid = threadIdx.x;
  const int lane = tid & 63, w = tid >> 6;
  const int g = (lane >> 4) & 3, ql = lane & 15;
  const int b = blockIdx.y;
  const int q0 = blockIdx.x * 64 + w * 16;
  const long bofs = (long)b * 4096;

  // Q fragments held in registers for the whole KV loop
  const short* Qb = Q + (bofs + q0 + ql) * 128;
  short8 qf[4];
  #pragma unroll
  for (int ds = 0; ds < 4; ++ds)
    qf[ds] = *(const short8*)(Qb + ds * 32 + g * 8);

  const f32x4 fzero = {0.f, 0.f, 0.f, 0.f};
  f32x4 acc[8];
  #pragma unroll
  for (int t = 0; t < 8; ++t) acc[t] = fzero;
  float mx = -1e30f, lsum = 0.f;

  const short* Kb  = K + bofs * 128;
  const short* VTb = VT + bofs;

  const int kr0 = tid >> 4, kd0 = (tid & 15) * 8;   // K staging: rows kr0, kr0+16
  const int vdv = tid >> 1, vch = (tid & 1) * 16;   // V^T staging: row vdv, cols vch..+15

  for (int it = 0; it < 128; ++it) {
    const int kv0 = it * 32;
    __syncthreads();
    // stage K tile [32][128]
    *(short8*)&Klds[kr0 * 136 + kd0] =
        *(const short8*)(Kb + (long)(kv0 + kr0) * 128 + kd0);
    *(short8*)&Klds[(kr0 + 16) * 136 + kd0] =
        *(const short8*)(Kb + (long)(kv0 + kr0 + 16) * 128 + kd0);
    // stage V^T tile [128][32]
    {
      const short* vs = VTb + (long)vdv * 32768 + kv0 + vch;
      *(short8*)&Vlds[vdv * 40 + vch]     = *(const short8*)vs;
      *(short8*)&Vlds[vdv * 40 + vch + 8] = *(const short8*)(vs + 8);
    }
    __syncthreads();

    // S^T = K · Q^T  (two 16-row k-halves, 4 d-slices)
    f32x4 st0 = fzero, st1 = fzero;
    #pragma unroll
    for (int ds = 0; ds < 4; ++ds) {
      short8 kf0 = *(const short8*)&Klds[ql * 136 + ds * 32 + g * 8];
      short8 kf1 = *(const short8*)&Klds[(16 + ql) * 136 + ds * 32 + g * 8];
      st0 = MFMA_16x16x32(kf0, qf[ds], st0);
      st1 = MFMA_16x16x32(kf1, qf[ds], st1);
    }

    // online softmax for q-column (lane&15); values spread over 4 lane-groups
    float tm = fmaxf(fmaxf(fmaxf(st0[0], st0[1]), fmaxf(st0[2], st0[3])),
                     fmaxf(fmaxf(st1[0], st1[1]), fmaxf(st1[2], st1[3])));
    tm = fmaxf(tm, __shfl_xor(tm, 16));
    tm = fmaxf(tm, __shfl_xor(tm, 32));
    float mn = fmaxf(mx, tm);
    float alpha = exp2f(mx - mn);
    float p0[4], p1[4], ts = 0.f;
    #pragma unroll
    for (int r = 0; r < 4; ++r) {
      p0[r] = exp2f(st0[r] - mn);
      p1[r] = exp2f(st1[r] - mn);
      ts += p0[r] + p1[r];
    }
    ts += __shfl_xor(ts, 16);
    ts += __shfl_xor(ts, 32);
    lsum = lsum * alpha + ts;
    mx = mn;
    #pragma unroll
    for (int t = 0; t < 8; ++t) acc[t] *= alpha;

    // transpose P^T from D-layout (row=4g'+r, col=q) to fragment layout (elem i = k=8g+i, col=q)
    const int srcA = ((g & 1) << 5) + ql;   // lane of source group 2*(g&1)
    const int srcB = srcA + 16;
    const bool hi = (g >= 2);
    float bvv[8];
    #pragma unroll
    for (int r = 0; r < 4; ++r) {
      float a0 = __shfl(p0[r], srcA);
      float a1 = __shfl(p1[r], srcA);
      bvv[r] = hi ? a1 : a0;
      float b0 = __shfl(p0[r], srcB);
      float b1 = __shfl(p1[r], srcB);
      bvv[4 + r] = hi ? b1 : b0;
    }
    short8 pf;
    #pragma unroll
    for (int i = 0; i < 8; ++i) pf[i] = f2bf(bvv[i]);

    // O^T += V^T · P^T   (8 dv-tiles of 16)
    #pragma unroll
    for (int t = 0; t < 8; ++t) {
      short8 vf = *(const short8*)&Vlds[(16 * t + ql) * 40 + g * 8];
      acc[t] = MFMA_16x16x32(vf, pf, acc[t]);
    }
  }

  const float rl = 1.f / lsum;
  float* Ob = O + (bofs + q0 + ql) * 128;
  #pragma unroll
  for (int t = 0; t < 8; ++t)
    #pragma unroll
    for (int r = 0; r < 4; ++r)
      Ob[16 * t + 4 * g + r] = acc[t][r] * rl;
}

extern "C" void kernel_launch(void* const* d_in, const int* in_sizes, int n_in,
                              void* d_out, int out_size, void* d_ws, size_t ws_size,
                              hipStream_t stream) {
  const float* query = (const float*)d_in[0];
  const float* key   = (const float*)d_in[1];
  const float* value = (const float*)d_in[2];
  const float* Wq = (const float*)d_in[3];
  const float* bq = (const float*)d_in[4];
  const float* Wk = (const float*)d_in[5];
  const float* bk = (const float*)d_in[6];
  const float* Wv = (const float*)d_in[7];
  const float* bv = (const float*)d_in[8];

  short* ws  = (short*)d_ws;
  short* Qs  = ws;                      // [32768][128] bf16 (scaled)
  short* Ks  = Qs + 4194304;            // [32768][128] bf16
  short* VTs = Ks + 4194304;            // [128][32768] bf16
  short* WqT = VTs + 4194304;           // [128][1024] bf16
  short* WkT = WqT + 131072;
  short* WvT = WkT + 131072;

  wt_kernel<<<dim3(512, 3), 256, 0, stream>>>(Wq, Wk, Wv, WqT, WkT, WvT);
  const float scale_q = 0.08838834764831845f * 1.4426950408889634f;  // 1/sqrt(128) * log2(e)
  proj_kernel<<<dim3(512, 3), 256, 0, stream>>>(query, key, value, WqT, WkT, WvT,
                                                bq, bk, bv, Qs, Ks, VTs, scale_q);
  attn_kernel<<<dim3(64, 8), 256, 0, stream>>>(Qs, Ks, VTs, (float*)d_out);
}

// Round 2
// 226.684 us; speedup vs baseline: 1.5206x; 1.5206x over previous
//
#include <hip/hip_runtime.h>
#include <hip/hip_bf16.h>

typedef __attribute__((ext_vector_type(8))) short short8;
typedef __attribute__((ext_vector_type(4))) float f32x4;
typedef __attribute__((ext_vector_type(16))) float f32x16;
typedef __attribute__((ext_vector_type(4))) unsigned int u32x4;

#define MFMA16(A, B, C) __builtin_amdgcn_mfma_f32_16x16x32_bf16((A), (B), (C), 0, 0, 0)
#define MFMA32(A, B, C) __builtin_amdgcn_mfma_f32_32x32x16_bf16((A), (B), (C), 0, 0, 0)

__device__ __forceinline__ short f2bf(float x) {
  unsigned u = __float_as_uint(x);
  return (short)((u + 0x7FFFu + ((u >> 16) & 1u)) >> 16);  // RNE; inputs finite
}

__device__ __forceinline__ unsigned cvtpk(float lo, float hi) {
  unsigned r;
  asm("v_cvt_pk_bf16_f32 %0, %1, %2" : "=v"(r) : "v"(lo), "v"(hi));
  return r;
}

__device__ __forceinline__ void gload16(const void* g, const void* s) {
  __builtin_amdgcn_global_load_lds(
      (const __attribute__((address_space(1))) unsigned int*)g,
      (__attribute__((address_space(3))) unsigned int*)s, 16, 0, 0);
}

// ---------------- weight transpose + bf16 convert: W[1024][128] -> WT[128][1024] ----------------
__global__ __launch_bounds__(256) void wt_kernel(
    const float* __restrict__ Wq, const float* __restrict__ Wk, const float* __restrict__ Wv,
    short* __restrict__ WqT, short* __restrict__ WkT, short* __restrict__ WvT)
{
  const float* W  = (blockIdx.y == 0) ? Wq  : (blockIdx.y == 1) ? Wk  : Wv;
  short*       WT = (blockIdx.y == 0) ? WqT : (blockIdx.y == 1) ? WkT : WvT;
  int idx = blockIdx.x * 256 + threadIdx.x;   // 0..131071
  int n = idx >> 10, k = idx & 1023;
  WT[idx] = f2bf(W[k * 128 + n]);
}

// ---------------- fused QKV projection ----------------
__global__ __launch_bounds__(256) void proj_kernel(
    const float* __restrict__ Aq, const float* __restrict__ Ak, const float* __restrict__ Av,
    const short* __restrict__ WqT, const short* __restrict__ WkT, const short* __restrict__ WvT,
    const float* __restrict__ bq, const float* __restrict__ bk, const float* __restrict__ bv,
    short* __restrict__ Qs, short* __restrict__ Ks, short* __restrict__ VTs,
    float scale_q)
{
  __shared__ short Alds[64 * 40];
  __shared__ short Wlds[128 * 40];
  const int y = blockIdx.y;
  const float* A    = (y == 0) ? Aq  : (y == 1) ? Ak  : Av;
  const short* WT   = (y == 0) ? WqT : (y == 1) ? WkT : WvT;
  const float* bias = (y == 0) ? bq  : (y == 1) ? bk  : bv;
  const int tid = threadIdx.x;
  const int lane = tid & 63, w = tid >> 6;
  const int g = (lane >> 4) & 3, ql = lane & 15;
  const long m0 = (long)blockIdx.x * 64;

  const f32x4 fzero = {0.f, 0.f, 0.f, 0.f};
  f32x4 acc[8];
  #pragma unroll
  for (int i = 0; i < 8; ++i) acc[i] = fzero;

  const int arow = tid >> 2, ac0 = (tid & 3) * 8;
  const int wn1 = (w >> 1) * 64, wm1 = (w & 1) * 32;
  const int wn2 = w * 32;

  for (int kk = 0; kk < 1024; kk += 32) {
    __syncthreads();
    {
      const float* src = A + (m0 + arow) * 1024 + kk + ac0;
      float4 a0 = *(const float4*)(src);
      float4 a1 = *(const float4*)(src + 4);
      short8 pb;
      pb[0] = f2bf(a0.x); pb[1] = f2bf(a0.y); pb[2] = f2bf(a0.z); pb[3] = f2bf(a0.w);
      pb[4] = f2bf(a1.x); pb[5] = f2bf(a1.y); pb[6] = f2bf(a1.z); pb[7] = f2bf(a1.w);
      *(short8*)&Alds[arow * 40 + ac0] = pb;
    }
    #pragma unroll
    for (int cc = 0; cc < 2; ++cc) {
      int c = tid + cc * 256;
      int n = c >> 2, i0 = (c & 3) * 8;
      *(short8*)&Wlds[n * 40 + i0] = *(const short8*)(WT + n * 1024 + kk + i0);
    }
    __syncthreads();
    if (y < 2) {
      short8 af[2], bf[4];
      #pragma unroll
      for (int mt = 0; mt < 2; ++mt)
        af[mt] = *(const short8*)&Alds[(wm1 + 16 * mt + ql) * 40 + g * 8];
      #pragma unroll
      for (int nt = 0; nt < 4; ++nt)
        bf[nt] = *(const short8*)&Wlds[(wn1 + 16 * nt + ql) * 40 + g * 8];
      #pragma unroll
      for (int mt = 0; mt < 2; ++mt)
        #pragma unroll
        for (int nt = 0; nt < 4; ++nt)
          acc[mt * 4 + nt] = MFMA16(af[mt], bf[nt], acc[mt * 4 + nt]);
    } else {
      short8 af[2], bf[4];
      #pragma unroll
      for (int nt = 0; nt < 2; ++nt)
        af[nt] = *(const short8*)&Wlds[(wn2 + 16 * nt + ql) * 40 + g * 8];
      #pragma unroll
      for (int mt = 0; mt < 4; ++mt)
        bf[mt] = *(const short8*)&Alds[(16 * mt + ql) * 40 + g * 8];
      #pragma unroll
      for (int nt = 0; nt < 2; ++nt)
        #pragma unroll
        for (int mt = 0; mt < 4; ++mt)
          acc[nt * 4 + mt] = MFMA16(af[nt], bf[mt], acc[nt * 4 + mt]);
    }
  }

  if (y < 2) {
    short* Out = (y == 0) ? Qs : Ks;
    const float sc = (y == 0) ? scale_q : 1.0f;
    #pragma unroll
    for (int nt = 0; nt < 4; ++nt) {
      int n = wn1 + 16 * nt + ql;
      float bs = bias[n];
      #pragma unroll
      for (int mt = 0; mt < 2; ++mt)
        #pragma unroll
        for (int r = 0; r < 4; ++r) {
          long m = m0 + wm1 + 16 * mt + 4 * g + r;
          Out[m * 128 + n] = f2bf((acc[mt * 4 + nt][r] + bs) * sc);
        }
    }
  } else {
    #pragma unroll
    for (int nt = 0; nt < 2; ++nt)
      #pragma unroll
      for (int r = 0; r < 4; ++r) {
        int n = wn2 + 16 * nt + 4 * g + r;
        float bs = bias[n];
        #pragma unroll
        for (int mt = 0; mt < 4; ++mt) {
          long m = m0 + 16 * mt + ql;
          VTs[(long)n * 32768 + m] = f2bf(acc[nt * 4 + mt][r] + bs);
        }
      }
  }
}

// ---------------- flash attention, 32x32 MFMA, 4 waves x 32 q-rows, KVBLK=64 ----------------
// Computes O^T[dv][q] partial over a kv-range; writes unnormalized acc + (m,l) stats.
__global__ __launch_bounds__(256, 2) void attn_kernel(
    const short* __restrict__ Q,    // [32768][128] bf16 (pre-scaled by 1/sqrt(128)*log2e)
    const short* __restrict__ K,    // [32768][128] bf16
    const short* __restrict__ VT,   // [128][32768] bf16
    float* __restrict__ O0,         // partial half0 (= d_out)
    float* __restrict__ O1,         // partial half1
    float2* __restrict__ stats,     // [halves][32768] {m, l}
    int ntiles)
{
  __shared__ short lds[32768];      // 2 bufs x (K [64][128] + VT [128][64]) = 64 KB
  const int tid = threadIdx.x, l = tid & 63, w = tid >> 6;
  const int l31 = l & 31, hi = l >> 5, xm = (l & 7) << 3;
  const int qb = blockIdx.x, h = blockIdx.y;
  const int b = qb >> 5;
  const int qrow = qb * 128 + w * 32 + l31;
  const long kv0 = (long)b * 4096 + (long)h * ntiles * 64;

  // Q fragments (B-operand: col = q = l31, k = d = ds*16 + hi*8 + i)
  short8 qf[8];
  const short* Qp = Q + (long)qrow * 128 + hi * 8;
  #pragma unroll
  for (int ds = 0; ds < 8; ++ds) qf[ds] = *(const short8*)(Qp + ds * 16);

  // staging source offsets (inverse-swizzled so linear LDS + swizzled reads match)
  const short* Kt = K + kv0 * 128;
  const short* Vt = VT + kv0;
  int kg_off[4]; long vg_off[4];
  #pragma unroll
  for (int r = 0; r < 4; ++r) {
    int c = r * 256 + tid;
    int p = c * 16;
    kg_off[r] = (p ^ (((p >> 8) & 7) << 4)) >> 1;        // K tile is contiguous [64][128]
    int e = (p ^ (((p >> 7) & 7) << 4)) >> 1;            // VT tile rows stride 32768
    vg_off[r] = (long)(e >> 6) * 32768 + (e & 63);
  }

  #define STAGE(bb, t) { \
    const short* kg_ = Kt + (t) * 8192; \
    const short* vg_ = Vt + (t) * 64; \
    _Pragma("unroll") \
    for (int r = 0; r < 4; ++r) { \
      gload16(kg_ + kg_off[r], &lds[(bb) * 16384 + r * 2048 + w * 512]); \
      gload16(vg_ + vg_off[r], &lds[(bb) * 16384 + 8192 + r * 2048 + w * 512]); \
    } }

  f32x16 acc0 = {}, acc1 = {}, acc2 = {}, acc3 = {};
  float m = -3e38f, lsum = 0.f;
  const int kread = l31 * 128;   // K lds row base (shorts); +4096 for rows 32..63

  STAGE(0, 0);

  for (int t = 0; t < ntiles; ++t) {
    const int bb = t & 1;
    if (t + 1 < ntiles) {
      STAGE(bb ^ 1, t + 1);
      asm volatile("s_waitcnt vmcnt(8)" ::: "memory");   // current tile's 8 done; next 8 in flight
    } else {
      asm volatile("s_waitcnt vmcnt(0)" ::: "memory");
    }
    __builtin_amdgcn_s_barrier();

    const short* kb = &lds[bb * 16384];
    const short* vb = &lds[bb * 16384 + 8192];

    // S^T = K · Q^T : two 32-kv tiles, 8 d-slices of 16
    f32x16 st0 = {}, st1 = {};
    #pragma unroll
    for (int ds = 0; ds < 8; ++ds) {
      int co = (ds * 16 + hi * 8) ^ xm;
      short8 kf0 = *(const short8*)(kb + kread + co);
      short8 kf1 = *(const short8*)(kb + 4096 + kread + co);
      st0 = MFMA32(kf0, qf[ds], st0);
      st1 = MFMA32(kf1, qf[ds], st1);
    }

    // in-register online softmax (lane owns q-column l31; lanes l and l+32 split kv rows)
    float a0 = fmaxf(fmaxf(st0[0], st0[1]),  fmaxf(st0[2], st0[3]));
    float a1 = fmaxf(fmaxf(st0[4], st0[5]),  fmaxf(st0[6], st0[7]));
    float a2 = fmaxf(fmaxf(st0[8], st0[9]),  fmaxf(st0[10], st0[11]));
    float a3 = fmaxf(fmaxf(st0[12], st0[13]), fmaxf(st0[14], st0[15]));
    float b0 = fmaxf(fmaxf(st1[0], st1[1]),  fmaxf(st1[2], st1[3]));
    float b1 = fmaxf(fmaxf(st1[4], st1[5]),  fmaxf(st1[6], st1[7]));
    float b2 = fmaxf(fmaxf(st1[8], st1[9]),  fmaxf(st1[10], st1[11]));
    float b3 = fmaxf(fmaxf(st1[12], st1[13]), fmaxf(st1[14], st1[15]));
    float pm = fmaxf(fmaxf(fmaxf(a0, a1), fmaxf(a2, a3)),
                     fmaxf(fmaxf(b0, b1), fmaxf(b2, b3)));
    pm = fmaxf(pm, __shfl_xor(pm, 32));
    if (!__all(pm <= m + 8.f)) {        // defer-max (T13): skip rescale when growth < 2^8
      float mn = fmaxf(m, pm);
      float al = exp2f(m - mn);
      m = mn;
      lsum *= al;
      acc0 *= al; acc1 *= al; acc2 *= al; acc3 *= al;
    }
    float ts = 0.f;
    #pragma unroll
    for (int j = 0; j < 16; ++j) { st0[j] = exp2f(st0[j] - m); ts += st0[j]; }
    #pragma unroll
    for (int j = 0; j < 16; ++j) { st1[j] = exp2f(st1[j] - m); ts += st1[j]; }
    ts += __shfl_xor(ts, 32);
    lsum += ts;

    // P -> bf16 B-frags: 16 cvt_pk + 8 permlane32_swap (T12)
    unsigned pk[16];
    #pragma unroll
    for (int j = 0; j < 8; ++j) pk[j]     = cvtpk(st0[2 * j], st0[2 * j + 1]);
    #pragma unroll
    for (int j = 0; j < 8; ++j) pk[8 + j] = cvtpk(st1[2 * j], st1[2 * j + 1]);

    // O^T += V^T · P^T : 4 dv-tiles x 4 kv-slices
    #pragma unroll
    for (int f = 0; f < 4; ++f) {
      auto r02 = __builtin_amdgcn_permlane32_swap(pk[f * 4 + 0], pk[f * 4 + 2], false, false);
      auto r13 = __builtin_amdgcn_permlane32_swap(pk[f * 4 + 1], pk[f * 4 + 3], false, false);
      union { u32x4 u; short8 s; } pf;
      pf.u = (u32x4){r02[0], r13[0], r02[1], r13[1]};
      int vo = (f * 16 + hi * 8) ^ xm;
      acc0 = MFMA32(*(const short8*)(vb +        l31 * 64 + vo), pf.s, acc0);
      acc1 = MFMA32(*(const short8*)(vb + 2048 + l31 * 64 + vo), pf.s, acc1);
      acc2 = MFMA32(*(const short8*)(vb + 4096 + l31 * 64 + vo), pf.s, acc2);
      acc3 = MFMA32(*(const short8*)(vb + 6144 + l31 * 64 + vo), pf.s, acc3);
    }

    asm volatile("s_waitcnt lgkmcnt(0)" ::: "memory");
    __builtin_amdgcn_s_barrier();
  }

  float* Op = ((h == 0) ? O0 : O1) + (long)qrow * 128;
  #define STORE_DT(A, dtb) { \
    _Pragma("unroll") \
    for (int jj = 0; jj < 4; ++jj) { \
      f32x4 o_ = {A[4 * jj], A[4 * jj + 1], A[4 * jj + 2], A[4 * jj + 3]}; \
      *(f32x4*)(Op + (dtb) + jj * 8 + hi * 4) = o_; \
    } }
  STORE_DT(acc0, 0) STORE_DT(acc1, 32) STORE_DT(acc2, 64) STORE_DT(acc3, 96)

  if (l < 32) stats[(long)h * 32768 + qrow] = make_float2(m, lsum);
}

// ---------------- merge partial halves ----------------
__global__ __launch_bounds__(256) void merge_kernel(
    float* __restrict__ O, const float* __restrict__ O1,
    const float2* __restrict__ stats, int halves)
{
  int idx = blockIdx.x * 256 + threadIdx.x;   // 32768*32 chunks of f32x4
  int q = idx >> 5, c = (idx & 31) * 4;
  long off = (long)q * 128 + c;
  float2 s0 = stats[q];
  f32x4 a = *(const f32x4*)(O + off);
  if (halves == 2) {
    float2 s1 = stats[32768 + q];
    float M = fmaxf(s0.x, s1.x);
    float w0 = exp2f(s0.x - M), w1 = exp2f(s1.x - M);
    f32x4 bv = *(const f32x4*)(O1 + off);
    float inv = 1.f / (w0 * s0.y + w1 * s1.y);
    a = (a * w0 + bv * w1) * inv;
  } else {
    a = a * (1.f / s0.y);
  }
  *(f32x4*)(O + off) = a;
}

extern "C" void kernel_launch(void* const* d_in, const int* in_sizes, int n_in,
                              void* d_out, int out_size, void* d_ws, size_t ws_size,
                              hipStream_t stream) {
  const float* query = (const float*)d_in[0];
  const float* key   = (const float*)d_in[1];
  const float* value = (const float*)d_in[2];
  const float* Wq = (const float*)d_in[3];
  const float* bq = (const float*)d_in[4];
  const float* Wk = (const float*)d_in[5];
  const float* bk = (const float*)d_in[6];
  const float* Wv = (const float*)d_in[7];
  const float* bv = (const float*)d_in[8];

  char* wsb = (char*)d_ws;
  short* Qs  = (short*)(wsb);                 // 8,388,608 B
  short* Ks  = (short*)(wsb + 8388608);       // 8,388,608 B
  short* VTs = (short*)(wsb + 16777216);      // 8,388,608 B
  short* WqT = (short*)(wsb + 25165824);      // 262,144 B
  short* WkT = (short*)(wsb + 25427968);
  short* WvT = (short*)(wsb + 25690112);      // ends 25,952,256
  float* O1  = (float*)(wsb + 25952256);      // 16,777,216 B (half-1 partial)
  const size_t NEED2 = 25952256ull + 16777216ull + 524288ull;   // 43.3 MB
  int halves = (ws_size >= NEED2) ? 2 : 1;
  float2* stats = (float2*)(wsb + (halves == 2 ? 42729472ull : 25952256ull));
  int ntiles = (halves == 2) ? 32 : 64;

  wt_kernel<<<dim3(512, 3), 256, 0, stream>>>(Wq, Wk, Wv, WqT, WkT, WvT);
  const float scale_q = 0.08838834764831845f * 1.4426950408889634f;  // 1/sqrt(128) * log2(e)
  proj_kernel<<<dim3(512, 3), 256, 0, stream>>>(query, key, value, WqT, WkT, WvT,
                                                bq, bk, bv, Qs, Ks, VTs, scale_q);
  attn_kernel<<<dim3(256, halves), 256, 0, stream>>>(Qs, Ks, VTs, (float*)d_out, O1, stats, ntiles);
  merge_kernel<<<4096, 256, 0, stream>>>((float*)d_out, O1, stats, halves);
}